// Round 8
// baseline (227.922 us; speedup 1.0000x reference)
//
#include <hip/hip_runtime.h>
#include <math.h>

#define BB 8
#define NN 512
#define FF 128
#define TT 32
#define DD 64
constexpr float EPS = 1e-6f;

typedef _Float16 half8 __attribute__((ext_vector_type(8)));
typedef _Float16 half4v __attribute__((ext_vector_type(4)));
typedef float f32x4 __attribute__((ext_vector_type(4)));

extern __shared__ char dynsmem[];

__device__ __forceinline__ float fast_tanh(float v) {
    float e = __expf(2.f * v);
    return 1.f - 2.f * __builtin_amdgcn_rcpf(e + 1.f);
}

__device__ __forceinline__ void gl_lds16(const void* g, void* l) {
    __builtin_amdgcn_global_load_lds((const __attribute__((address_space(1))) unsigned int*)g,
                                     (__attribute__((address_space(3))) unsigned int*)l,
                                     16, 0, 0);
}

// ---------------- Stage 1: z = tanh(x @ W^T + b) -> fp16 hi/lo split, swizzled d-major ----------------
// z layout: [b][t][n][octet ^ (n&7)][8]
// grid: B * (N/2) = 2048 blocks, 256 threads
__global__ __launch_bounds__(256) void z_kernel(const float* __restrict__ x,
                                                const float* __restrict__ W,
                                                const float* __restrict__ bias,
                                                _Float16* __restrict__ zh,
                                                _Float16* __restrict__ zl,
                                                float* __restrict__ sqv,
                                                float* __restrict__ nvv) {
    float* lds = (float*)dynsmem;
    float* xs = lds;                      // 2*32*132 floats
    float* Wt = lds + 2 * 32 * 132;       // 128*64 floats
    const int tid = threadIdx.x;
    const int b  = blockIdx.x >> 8;
    const int n0 = (blockIdx.x & 255) * 2;

    const float4* W4 = (const float4*)W;
    #pragma unroll
    for (int it = 0; it < 8; ++it) {
        int idx4 = tid + it * 256;
        float4 w = W4[idx4];
        int d = idx4 >> 5;
        int f = (idx4 & 31) * 4;
        Wt[(f + 0) * 64 + d] = w.x;
        Wt[(f + 1) * 64 + d] = w.y;
        Wt[(f + 2) * 64 + d] = w.z;
        Wt[(f + 3) * 64 + d] = w.w;
    }
    const float4* x4 = (const float4*)(x + ((size_t)b * NN + n0) * FF * TT);
    #pragma unroll
    for (int it = 0; it < 8; ++it) {
        int idx4 = tid + it * 256;
        float4 v = x4[idx4];
        int e   = idx4 * 4;
        int ns  = e >> 12;
        int rem = e & 4095;
        int f   = rem >> 5;
        int t   = rem & 31;
        float* base = xs + ns * (32 * 132) + t * 132 + f;
        base[0 * 132] = v.x;
        base[1 * 132] = v.y;
        base[2 * 132] = v.z;
        base[3 * 132] = v.w;
    }
    __syncthreads();

    const int t  = tid >> 3;
    const int dg = tid & 7;
    const int d0 = dg * 8;
    float acc[2][8];
    #pragma unroll
    for (int ns = 0; ns < 2; ++ns)
        #pragma unroll
        for (int dd = 0; dd < 8; ++dd) acc[ns][dd] = 0.f;

    #pragma unroll 4
    for (int fc = 0; fc < FF; fc += 4) {
        float wv[4][8];
        #pragma unroll
        for (int k = 0; k < 4; ++k) {
            float4 a = *(const float4*)&Wt[(fc + k) * 64 + d0];
            float4 c = *(const float4*)&Wt[(fc + k) * 64 + d0 + 4];
            wv[k][0] = a.x; wv[k][1] = a.y; wv[k][2] = a.z; wv[k][3] = a.w;
            wv[k][4] = c.x; wv[k][5] = c.y; wv[k][6] = c.z; wv[k][7] = c.w;
        }
        #pragma unroll
        for (int ns = 0; ns < 2; ++ns) {
            float4 xv = *(const float4*)&xs[ns * (32 * 132) + t * 132 + fc];
            float xk[4] = {xv.x, xv.y, xv.z, xv.w};
            #pragma unroll
            for (int dd = 0; dd < 8; ++dd) {
                acc[ns][dd] += xk[0] * wv[0][dd] + xk[1] * wv[1][dd]
                             + xk[2] * wv[2][dd] + xk[3] * wv[3][dd];
            }
        }
    }

    float bb[8];
    #pragma unroll
    for (int dd = 0; dd < 8; ++dd) bb[dd] = bias[d0 + dd];

    const size_t rowbase = ((size_t)b * TT + t) * NN + n0;
    float sqp[2];
    #pragma unroll
    for (int ns = 0; ns < 2; ++ns) {
        half8 hv, lv;
        float sp = 0.f;
        #pragma unroll
        for (int dd = 0; dd < 8; ++dd) {
            float zf = fast_tanh(acc[ns][dd] + bb[dd]);
            sp += zf * zf;
            _Float16 h = (_Float16)zf;
            hv[dd] = h;
            lv[dd] = (_Float16)(zf - (float)h);
        }
        size_t off = (rowbase + ns) * DD + (size_t)((dg ^ ((n0 + ns) & 7)) * 8);
        *(half8*)(zh + off) = hv;
        *(half8*)(zl + off) = lv;
        sqp[ns] = sp;
    }
    #pragma unroll
    for (int k = 1; k < 8; k <<= 1) {
        #pragma unroll
        for (int ns = 0; ns < 2; ++ns) sqp[ns] += __shfl_xor(sqp[ns], k);
    }
    if (dg == 0) {
        #pragma unroll
        for (int ns = 0; ns < 2; ++ns) {
            sqv[rowbase + ns] = sqp[ns];
            nvv[rowbase + ns] = sqrtf(sqp[ns]) + EPS;
        }
    }
}

// ---------------- Stage 2: quarter-staged slab, split-fp16 MFMA, 2 blocks/CU ----------------
// grid: 512 blocks (t = bid&31, rowgroup32 = bid>>5), 512 threads = 8 waves.
// wave w: rowtile rt=w>>2 (16 rows), colgroup cg=w&3 (32 cols per staged 128-col quarter).
// Quarters iterated cyclically starting at the block's own-row quarter (A-frags from LDS).
#define NORMOFS 65536
#define RSOFS   73728
#define LDSSZ_ATT 74240

__global__ __launch_bounds__(512, 4) void att7_kernel(const _Float16* __restrict__ zh,
                                                      const _Float16* __restrict__ zl,
                                                      const float* __restrict__ sqv,
                                                      const float* __restrict__ nvv,
                                                      float* __restrict__ out) {
    char* lds = dynsmem;
    const int tid  = threadIdx.x;
    const int w    = tid >> 6;
    const int lane = tid & 63;
    const int l15  = lane & 15;
    const int g    = lane >> 4;
    const int rt   = w >> 2;
    const int cg   = w & 3;
    const int t    = blockIdx.x & 31;
    const int rg   = blockIdx.x >> 5;
    const int n0   = rg * 32;
    const int qs   = rg >> 2;            // quarter containing this block's rows

    auto stage_quarter = [&](int qc, int bq, int buf) {
        const size_t slab = ((size_t)bq * TT + t) * (size_t)(NN * DD * 2);  // bytes per slab
        const char* sh = (const char*)zh + slab + qc * 16384 + tid * 16;
        const char* sl = (const char*)zl + slab + qc * 16384 + tid * 16;
        char* dh = lds + buf * 32768 + tid * 16;
        char* dl = lds + buf * 32768 + 16384 + tid * 16;
        gl_lds16(sh,        dh);
        gl_lds16(sh + 8192, dh + 8192);
        gl_lds16(sl,        dl);
        gl_lds16(sl + 8192, dl + 8192);
    };
    auto stage_norms = [&](int bn) {
        const int pb = bn & 1;
        const size_t nbyte = (((size_t)bn * TT + t) * NN) * 4;
        if (w < 2) {
            gl_lds16((const char*)nvv + nbyte + w * 1024 + lane * 16,
                     lds + NORMOFS + pb * 4096 + w * 1024 + lane * 16);
        } else if (w < 4) {
            gl_lds16((const char*)sqv + nbyte + (w - 2) * 1024 + lane * 16,
                     lds + NORMOFS + pb * 4096 + 2048 + (w - 2) * 1024 + lane * 16);
        }
    };

    stage_quarter(qs, 0, 0);
    stage_norms(0);
    __syncthreads();

    float acc[8][4];
    #pragma unroll
    for (int ct = 0; ct < 8; ++ct)
        #pragma unroll
        for (int ri = 0; ri < 4; ++ri) acc[ct][ri] = 0.f;

    half4v atth[8];
    int buf = 0;

    for (int b = 0; b < BB; ++b) {
        const int pb = b & 1;

        // A fragments from LDS buf (own quarter staged): rows n0 + rt*16 + l15
        const int arow = n0 + rt * 16 + l15;
        const int cl   = arow & 127;
        const int ak   = arow & 7;
        half8 ah[2], al[2];
        {
            const char* ab = lds + buf * 32768;
            ah[0] = *(const half8*)(ab + cl * 128 + (((0 + g) ^ ak) << 4));
            ah[1] = *(const half8*)(ab + cl * 128 + (((4 + g) ^ ak) << 4));
            al[0] = *(const half8*)(ab + 16384 + cl * 128 + (((0 + g) ^ ak) << 4));
            al[1] = *(const half8*)(ab + 16384 + cl * 128 + (((4 + g) ^ ak) << 4));
        }

        float nr[4], sq_r[4], nri[4];
        #pragma unroll
        for (int ri = 0; ri < 4; ++ri) {
            const int rrow = n0 + rt * 16 + g * 4 + ri;
            nr[ri]   = *(const float*)(lds + NORMOFS + pb * 4096 + rrow * 4);
            sq_r[ri] = *(const float*)(lds + NORMOFS + pb * 4096 + 2048 + rrow * 4);
            nri[ri]  = __builtin_amdgcn_rcpf(nr[ri]);
        }

        float rs[4] = {0.f, 0.f, 0.f, 0.f};

        #pragma unroll
        for (int q = 0; q < 4; ++q) {
            if (q < 3)            stage_quarter((qs + q + 1) & 3, b, buf ^ 1);
            else if (b < BB - 1) { stage_quarter(qs, b + 1, buf ^ 1); stage_norms(b + 1); }

            const int qc = (qs + q) & 3;
            #pragma unroll
            for (int ct = 0; ct < 2; ++ct) {
                const int cti = q * 2 + ct;
                const int clq = cg * 32 + ct * 16 + l15;
                const int col = qc * 128 + clq;
                const int kk  = col & 7;
                const char* bbse = lds + buf * 32768;
                half8 bh0 = *(const half8*)(bbse + clq * 128 + (((0 + g) ^ kk) << 4));
                half8 bh1 = *(const half8*)(bbse + clq * 128 + (((4 + g) ^ kk) << 4));
                half8 bl0 = *(const half8*)(bbse + 16384 + clq * 128 + (((0 + g) ^ kk) << 4));
                half8 bl1 = *(const half8*)(bbse + 16384 + clq * 128 + (((4 + g) ^ kk) << 4));

                f32x4 dhh = {0.f, 0.f, 0.f, 0.f};
                f32x4 dhl = {0.f, 0.f, 0.f, 0.f};
                f32x4 dlh = {0.f, 0.f, 0.f, 0.f};
                dhh = __builtin_amdgcn_mfma_f32_16x16x32_f16(ah[0], bh0, dhh, 0, 0, 0);
                dhl = __builtin_amdgcn_mfma_f32_16x16x32_f16(ah[0], bl0, dhl, 0, 0, 0);
                dlh = __builtin_amdgcn_mfma_f32_16x16x32_f16(al[0], bh0, dlh, 0, 0, 0);
                dhh = __builtin_amdgcn_mfma_f32_16x16x32_f16(ah[1], bh1, dhh, 0, 0, 0);
                dhl = __builtin_amdgcn_mfma_f32_16x16x32_f16(ah[1], bl1, dhl, 0, 0, 0);
                dlh = __builtin_amdgcn_mfma_f32_16x16x32_f16(al[1], bh1, dlh, 0, 0, 0);
                f32x4 d = dhh + dhl + dlh;

                const float nm  = *(const float*)(lds + NORMOFS + pb * 4096 + col * 4);
                const float sqm = *(const float*)(lds + NORMOFS + pb * 4096 + 2048 + col * 4);
                const float nmi = __builtin_amdgcn_rcpf(nm);
                #pragma unroll
                for (int ri = 0; ri < 4; ++ri) {
                    float dot = d[ri];
                    float cs  = dot * nri[ri] * nmi;
                    float d2  = fmaxf(fmaf(dot, -2.f, sq_r[ri] + sqm), 0.f);
                    float dn  = __builtin_amdgcn_sqrtf(d2);
                    float a   = __expf(fmaf(dn, -__builtin_amdgcn_rcpf(nr[ri] + nm + EPS), cs));
                    atth[cti][ri] = (_Float16)a;
                    rs[ri] += a;
                }
            }
            __syncthreads();
            buf ^= 1;
        }

        #pragma unroll
        for (int ri = 0; ri < 4; ++ri) {
            float v = rs[ri];
            v += __shfl_xor(v, 1);
            v += __shfl_xor(v, 2);
            v += __shfl_xor(v, 4);
            v += __shfl_xor(v, 8);
            rs[ri] = v;
        }
        if (l15 == 0) {
            #pragma unroll
            for (int ri = 0; ri < 4; ++ri)
                *(float*)(lds + RSOFS + ((rt * 4 + cg) * 16 + g * 4 + ri) * 4) = rs[ri];
        }
        __syncthreads();
        #pragma unroll
        for (int ri = 0; ri < 4; ++ri) {
            const int rl = g * 4 + ri;
            float tot = *(const float*)(lds + RSOFS + ((rt * 4 + 0) * 16 + rl) * 4)
                      + *(const float*)(lds + RSOFS + ((rt * 4 + 1) * 16 + rl) * 4)
                      + *(const float*)(lds + RSOFS + ((rt * 4 + 2) * 16 + rl) * 4)
                      + *(const float*)(lds + RSOFS + ((rt * 4 + 3) * 16 + rl) * 4);
            float rinv = __builtin_amdgcn_rcpf(tot + EPS);
            #pragma unroll
            for (int ct = 0; ct < 8; ++ct)
                acc[ct][ri] += (float)atth[ct][ri] * rinv;
        }
    }

    // out epilogue: two 16-row LDS-transpose rounds (dbuf dead)
    for (int r = 0; r < 2; ++r) {
        if (rt == r) {
            #pragma unroll
            for (int ri = 0; ri < 4; ++ri)
                #pragma unroll
                for (int ct = 0; ct < 8; ++ct) {
                    const int col = ((qs + (ct >> 1)) & 3) * 128 + cg * 32 + (ct & 1) * 16 + l15;
                    *(float*)(lds + ((g * 4 + ri) * 516 + col) * 4) = acc[ct][ri] * 0.125f;
                }
        }
        __syncthreads();
        #pragma unroll
        for (int it = 0; it < 4; ++it) {
            const int idx4 = tid + it * 512;
            const int row  = idx4 >> 7;
            const int cc   = (idx4 & 127) * 4;
            float4 v = *(const float4*)(lds + (row * 516 + cc) * 4);
            *(float4*)(out + ((size_t)t * NN + n0 + r * 16 + row) * NN + cc) = v;
        }
        __syncthreads();
    }
}

extern "C" void kernel_launch(void* const* d_in, const int* in_sizes, int n_in,
                              void* d_out, int out_size, void* d_ws, size_t ws_size,
                              hipStream_t stream) {
    const float* x    = (const float*)d_in[0];
    const float* W    = (const float*)d_in[1];
    const float* bias = (const float*)d_in[2];
    float* out = (float*)d_out;

    const size_t ZELEMS = (size_t)BB * TT * NN * DD;
    _Float16* zh = (_Float16*)d_ws;
    _Float16* zl = zh + ZELEMS;
    float* sqv = (float*)(zh + 2 * ZELEMS);
    float* nvv = sqv + (size_t)BB * TT * NN;

    z_kernel<<<dim3(BB * (NN / 2)), dim3(256), 66560, stream>>>(x, W, bias, zh, zl, sqv, nvv);
    att7_kernel<<<dim3(TT * (NN / 32)), dim3(512), LDSSZ_ATT, stream>>>(zh, zl, sqv, nvv, out);
}

// Round 9
// 149.398 us; speedup vs baseline: 1.5256x; 1.5256x over previous
//
#include <hip/hip_runtime.h>
#include <math.h>

#define BB 8
#define NN 512
#define FF 128
#define TT 32
#define DD 64
constexpr float EPS = 1e-6f;

typedef _Float16 half8 __attribute__((ext_vector_type(8)));
typedef _Float16 half4v __attribute__((ext_vector_type(4)));
typedef float f32x4 __attribute__((ext_vector_type(4)));

extern __shared__ char dynsmem[];

__device__ __forceinline__ float fast_tanh(float v) {
    float e = __expf(2.f * v);
    return 1.f - 2.f * __builtin_amdgcn_rcpf(e + 1.f);
}

__device__ __forceinline__ void gl_lds16(const void* g, void* l) {
    __builtin_amdgcn_global_load_lds((const __attribute__((address_space(1))) unsigned int*)g,
                                     (__attribute__((address_space(3))) unsigned int*)l,
                                     16, 0, 0);
}

// ---------------- Stage 1: z = tanh(x @ W^T + b) -> fp16 hi/lo split, swizzled d-major ----------------
// z layout: [b][t][n][octet ^ (n&7)][8]
// grid: B * (N/2) = 2048 blocks, 256 threads
__global__ __launch_bounds__(256) void z_kernel(const float* __restrict__ x,
                                                const float* __restrict__ W,
                                                const float* __restrict__ bias,
                                                _Float16* __restrict__ zh,
                                                _Float16* __restrict__ zl,
                                                float* __restrict__ sqv,
                                                float* __restrict__ nvv) {
    float* lds = (float*)dynsmem;
    float* xs = lds;                      // 2*32*132 floats
    float* Wt = lds + 2 * 32 * 132;       // 128*64 floats
    const int tid = threadIdx.x;
    const int b  = blockIdx.x >> 8;
    const int n0 = (blockIdx.x & 255) * 2;

    const float4* W4 = (const float4*)W;
    #pragma unroll
    for (int it = 0; it < 8; ++it) {
        int idx4 = tid + it * 256;
        float4 w = W4[idx4];
        int d = idx4 >> 5;
        int f = (idx4 & 31) * 4;
        Wt[(f + 0) * 64 + d] = w.x;
        Wt[(f + 1) * 64 + d] = w.y;
        Wt[(f + 2) * 64 + d] = w.z;
        Wt[(f + 3) * 64 + d] = w.w;
    }
    const float4* x4 = (const float4*)(x + ((size_t)b * NN + n0) * FF * TT);
    #pragma unroll
    for (int it = 0; it < 8; ++it) {
        int idx4 = tid + it * 256;
        float4 v = x4[idx4];
        int e   = idx4 * 4;
        int ns  = e >> 12;
        int rem = e & 4095;
        int f   = rem >> 5;
        int t   = rem & 31;
        float* base = xs + ns * (32 * 132) + t * 132 + f;
        base[0 * 132] = v.x;
        base[1 * 132] = v.y;
        base[2 * 132] = v.z;
        base[3 * 132] = v.w;
    }
    __syncthreads();

    const int t  = tid >> 3;
    const int dg = tid & 7;
    const int d0 = dg * 8;
    float acc[2][8];
    #pragma unroll
    for (int ns = 0; ns < 2; ++ns)
        #pragma unroll
        for (int dd = 0; dd < 8; ++dd) acc[ns][dd] = 0.f;

    #pragma unroll 4
    for (int fc = 0; fc < FF; fc += 4) {
        float wv[4][8];
        #pragma unroll
        for (int k = 0; k < 4; ++k) {
            float4 a = *(const float4*)&Wt[(fc + k) * 64 + d0];
            float4 c = *(const float4*)&Wt[(fc + k) * 64 + d0 + 4];
            wv[k][0] = a.x; wv[k][1] = a.y; wv[k][2] = a.z; wv[k][3] = a.w;
            wv[k][4] = c.x; wv[k][5] = c.y; wv[k][6] = c.z; wv[k][7] = c.w;
        }
        #pragma unroll
        for (int ns = 0; ns < 2; ++ns) {
            float4 xv = *(const float4*)&xs[ns * (32 * 132) + t * 132 + fc];
            float xk[4] = {xv.x, xv.y, xv.z, xv.w};
            #pragma unroll
            for (int dd = 0; dd < 8; ++dd) {
                acc[ns][dd] += xk[0] * wv[0][dd] + xk[1] * wv[1][dd]
                             + xk[2] * wv[2][dd] + xk[3] * wv[3][dd];
            }
        }
    }

    float bb[8];
    #pragma unroll
    for (int dd = 0; dd < 8; ++dd) bb[dd] = bias[d0 + dd];

    const size_t rowbase = ((size_t)b * TT + t) * NN + n0;
    float sqp[2];
    #pragma unroll
    for (int ns = 0; ns < 2; ++ns) {
        half8 hv, lv;
        float sp = 0.f;
        #pragma unroll
        for (int dd = 0; dd < 8; ++dd) {
            float zf = fast_tanh(acc[ns][dd] + bb[dd]);
            sp += zf * zf;
            _Float16 h = (_Float16)zf;
            hv[dd] = h;
            lv[dd] = (_Float16)(zf - (float)h);
        }
        size_t off = (rowbase + ns) * DD + (size_t)((dg ^ ((n0 + ns) & 7)) * 8);
        *(half8*)(zh + off) = hv;
        *(half8*)(zl + off) = lv;
        sqp[ns] = sp;
    }
    #pragma unroll
    for (int k = 1; k < 8; k <<= 1) {
        #pragma unroll
        for (int ns = 0; ns < 2; ++ns) sqp[ns] += __shfl_xor(sqp[ns], k);
    }
    if (dg == 0) {
        #pragma unroll
        for (int ns = 0; ns < 2; ++ns) {
            sqv[rowbase + ns] = sqp[ns];
            nvv[rowbase + ns] = sqrtf(sqp[ns]) + EPS;
        }
    }
}

// ---------------- Stage 2: quarter-staged slab, split-fp16 MFMA, 2 blocks/CU ----------------
// grid: 512 blocks (t = bid&31, rowgroup32 = bid>>5), 512 threads = 8 waves.
// wave w: rowtile rt=w>>2 (16 rows), colgroup cg=w&3 (32 cols per staged 128-col quarter).
// __launch_bounds__(512, 2): VGPR cap 256 -> no spill (the (512,4) variant capped at 64 VGPR
// and generated ~330 MB of scratch spill traffic each way).
#define NORMOFS 65536
#define RSOFS   73728
#define LDSSZ_ATT 74240

__global__ __launch_bounds__(512, 2) void att8_kernel(const _Float16* __restrict__ zh,
                                                      const _Float16* __restrict__ zl,
                                                      const float* __restrict__ sqv,
                                                      const float* __restrict__ nvv,
                                                      float* __restrict__ out) {
    char* lds = dynsmem;
    const int tid  = threadIdx.x;
    const int w    = tid >> 6;
    const int lane = tid & 63;
    const int l15  = lane & 15;
    const int g    = lane >> 4;
    const int rt   = w >> 2;
    const int cg   = w & 3;
    const int t    = blockIdx.x & 31;
    const int rg   = blockIdx.x >> 5;
    const int n0   = rg * 32;
    const int qs   = rg >> 2;            // quarter containing this block's rows

    auto stage_quarter = [&](int qc, int bq, int buf) {
        const size_t slab = ((size_t)bq * TT + t) * (size_t)(NN * DD * 2);  // bytes per slab
        const char* sh = (const char*)zh + slab + qc * 16384 + tid * 16;
        const char* sl = (const char*)zl + slab + qc * 16384 + tid * 16;
        char* dh = lds + buf * 32768 + tid * 16;
        char* dl = lds + buf * 32768 + 16384 + tid * 16;
        gl_lds16(sh,        dh);
        gl_lds16(sh + 8192, dh + 8192);
        gl_lds16(sl,        dl);
        gl_lds16(sl + 8192, dl + 8192);
    };
    auto stage_norms = [&](int bn) {
        const int pb = bn & 1;
        const size_t nbyte = (((size_t)bn * TT + t) * NN) * 4;
        if (w < 2) {
            gl_lds16((const char*)nvv + nbyte + w * 1024 + lane * 16,
                     lds + NORMOFS + pb * 4096 + w * 1024 + lane * 16);
        } else if (w < 4) {
            gl_lds16((const char*)sqv + nbyte + (w - 2) * 1024 + lane * 16,
                     lds + NORMOFS + pb * 4096 + 2048 + (w - 2) * 1024 + lane * 16);
        }
    };

    stage_quarter(qs, 0, 0);
    stage_norms(0);
    __syncthreads();

    float acc[8][4];
    #pragma unroll
    for (int ct = 0; ct < 8; ++ct)
        #pragma unroll
        for (int ri = 0; ri < 4; ++ri) acc[ct][ri] = 0.f;

    half4v atth[8];
    int buf = 0;

    for (int b = 0; b < BB; ++b) {
        const int pb = b & 1;

        // A fragments from LDS buf (own quarter staged): rows n0 + rt*16 + l15
        const int arow = n0 + rt * 16 + l15;
        const int cl   = arow & 127;
        const int ak   = arow & 7;
        half8 ah[2], al[2];
        {
            const char* ab = lds + buf * 32768;
            ah[0] = *(const half8*)(ab + cl * 128 + (((0 + g) ^ ak) << 4));
            ah[1] = *(const half8*)(ab + cl * 128 + (((4 + g) ^ ak) << 4));
            al[0] = *(const half8*)(ab + 16384 + cl * 128 + (((0 + g) ^ ak) << 4));
            al[1] = *(const half8*)(ab + 16384 + cl * 128 + (((4 + g) ^ ak) << 4));
        }

        float nr[4], sq_r[4], nri[4];
        #pragma unroll
        for (int ri = 0; ri < 4; ++ri) {
            const int rrow = n0 + rt * 16 + g * 4 + ri;
            nr[ri]   = *(const float*)(lds + NORMOFS + pb * 4096 + rrow * 4);
            sq_r[ri] = *(const float*)(lds + NORMOFS + pb * 4096 + 2048 + rrow * 4);
            nri[ri]  = __builtin_amdgcn_rcpf(nr[ri]);
        }

        float rs[4] = {0.f, 0.f, 0.f, 0.f};

        #pragma unroll
        for (int q = 0; q < 4; ++q) {
            if (q < 3)            stage_quarter((qs + q + 1) & 3, b, buf ^ 1);
            else if (b < BB - 1) { stage_quarter(qs, b + 1, buf ^ 1); stage_norms(b + 1); }

            const int qc = (qs + q) & 3;
            #pragma unroll
            for (int ct = 0; ct < 2; ++ct) {
                const int cti = q * 2 + ct;
                const int clq = cg * 32 + ct * 16 + l15;
                const int col = qc * 128 + clq;
                const int kk  = col & 7;
                const char* bbse = lds + buf * 32768;
                half8 bh0 = *(const half8*)(bbse + clq * 128 + (((0 + g) ^ kk) << 4));
                half8 bh1 = *(const half8*)(bbse + clq * 128 + (((4 + g) ^ kk) << 4));
                half8 bl0 = *(const half8*)(bbse + 16384 + clq * 128 + (((0 + g) ^ kk) << 4));
                half8 bl1 = *(const half8*)(bbse + 16384 + clq * 128 + (((4 + g) ^ kk) << 4));

                f32x4 dhh = {0.f, 0.f, 0.f, 0.f};
                f32x4 dhl = {0.f, 0.f, 0.f, 0.f};
                f32x4 dlh = {0.f, 0.f, 0.f, 0.f};
                dhh = __builtin_amdgcn_mfma_f32_16x16x32_f16(ah[0], bh0, dhh, 0, 0, 0);
                dhl = __builtin_amdgcn_mfma_f32_16x16x32_f16(ah[0], bl0, dhl, 0, 0, 0);
                dlh = __builtin_amdgcn_mfma_f32_16x16x32_f16(al[0], bh0, dlh, 0, 0, 0);
                dhh = __builtin_amdgcn_mfma_f32_16x16x32_f16(ah[1], bh1, dhh, 0, 0, 0);
                dhl = __builtin_amdgcn_mfma_f32_16x16x32_f16(ah[1], bl1, dhl, 0, 0, 0);
                dlh = __builtin_amdgcn_mfma_f32_16x16x32_f16(al[1], bh1, dlh, 0, 0, 0);
                f32x4 d = dhh + dhl + dlh;

                const float nm  = *(const float*)(lds + NORMOFS + pb * 4096 + col * 4);
                const float sqm = *(const float*)(lds + NORMOFS + pb * 4096 + 2048 + col * 4);
                const float nmi = __builtin_amdgcn_rcpf(nm);
                #pragma unroll
                for (int ri = 0; ri < 4; ++ri) {
                    float dot = d[ri];
                    float cs  = dot * nri[ri] * nmi;
                    float d2  = fmaxf(fmaf(dot, -2.f, sq_r[ri] + sqm), 0.f);
                    float dn  = __builtin_amdgcn_sqrtf(d2);
                    float a   = __expf(fmaf(dn, -__builtin_amdgcn_rcpf(nr[ri] + nm + EPS), cs));
                    atth[cti][ri] = (_Float16)a;
                    rs[ri] += a;
                }
            }

            if (q == 3) {
                // fold rs exchange into the q3 barrier
                #pragma unroll
                for (int ri = 0; ri < 4; ++ri) {
                    float v = rs[ri];
                    v += __shfl_xor(v, 1);
                    v += __shfl_xor(v, 2);
                    v += __shfl_xor(v, 4);
                    v += __shfl_xor(v, 8);
                    rs[ri] = v;
                }
                if (l15 == 0) {
                    #pragma unroll
                    for (int ri = 0; ri < 4; ++ri)
                        *(float*)(lds + RSOFS + ((rt * 4 + cg) * 16 + g * 4 + ri) * 4) = rs[ri];
                }
            }
            __syncthreads();
            buf ^= 1;
        }

        #pragma unroll
        for (int ri = 0; ri < 4; ++ri) {
            const int rl = g * 4 + ri;
            float tot = *(const float*)(lds + RSOFS + ((rt * 4 + 0) * 16 + rl) * 4)
                      + *(const float*)(lds + RSOFS + ((rt * 4 + 1) * 16 + rl) * 4)
                      + *(const float*)(lds + RSOFS + ((rt * 4 + 2) * 16 + rl) * 4)
                      + *(const float*)(lds + RSOFS + ((rt * 4 + 3) * 16 + rl) * 4);
            float rinv = __builtin_amdgcn_rcpf(tot + EPS);
            #pragma unroll
            for (int ct = 0; ct < 8; ++ct)
                acc[ct][ri] += (float)atth[ct][ri] * rinv;
        }
    }

    // out epilogue: two 16-row LDS-transpose rounds (dbuf dead)
    __syncthreads();
    for (int r = 0; r < 2; ++r) {
        if (rt == r) {
            #pragma unroll
            for (int ri = 0; ri < 4; ++ri)
                #pragma unroll
                for (int ct = 0; ct < 8; ++ct) {
                    const int col = ((qs + (ct >> 1)) & 3) * 128 + cg * 32 + (ct & 1) * 16 + l15;
                    *(float*)(lds + ((g * 4 + ri) * 516 + col) * 4) = acc[ct][ri] * 0.125f;
                }
        }
        __syncthreads();
        #pragma unroll
        for (int it = 0; it < 4; ++it) {
            const int idx4 = tid + it * 512;
            const int row  = idx4 >> 7;
            const int cc   = (idx4 & 127) * 4;
            float4 v = *(const float4*)(lds + (row * 516 + cc) * 4);
            *(float4*)(out + ((size_t)t * NN + n0 + r * 16 + row) * NN + cc) = v;
        }
        __syncthreads();
    }
}

extern "C" void kernel_launch(void* const* d_in, const int* in_sizes, int n_in,
                              void* d_out, int out_size, void* d_ws, size_t ws_size,
                              hipStream_t stream) {
    const float* x    = (const float*)d_in[0];
    const float* W    = (const float*)d_in[1];
    const float* bias = (const float*)d_in[2];
    float* out = (float*)d_out;

    const size_t ZELEMS = (size_t)BB * TT * NN * DD;
    _Float16* zh = (_Float16*)d_ws;
    _Float16* zl = zh + ZELEMS;
    float* sqv = (float*)(zh + 2 * ZELEMS);
    float* nvv = sqv + (size_t)BB * TT * NN;

    z_kernel<<<dim3(BB * (NN / 2)), dim3(256), 66560, stream>>>(x, W, bias, zh, zl, sqv, nvv);
    att8_kernel<<<dim3(TT * (NN / 32)), dim3(512), LDSSZ_ATT, stream>>>(zh, zl, sqv, nvv, out);
}